// Round 6
// baseline (400.759 us; speedup 1.0000x reference)
//
#include <hip/hip_runtime.h>

#define B_ 8
#define N_ 8192
#define S_ 2048
#define D1_ 128
#define D2_ 256
#define C0_ 384
#define C1_ 256
#define C2_ 128
#define BN_EPS 1e-5f

typedef unsigned long long ull;
typedef unsigned short u16;
typedef __bf16 bf16x8 __attribute__((ext_vector_type(8)));
typedef float f32x4 __attribute__((ext_vector_type(4)));
typedef short short8_ __attribute__((ext_vector_type(8)));

__device__ __forceinline__ u16 f2bf(float x) {
  unsigned int u = __float_as_uint(x);
  unsigned int r = u + 0x7fffu + ((u >> 16) & 1u);
  return (u16)(r >> 16);
}
__device__ __forceinline__ float bf2f(u16 h) {
  return __uint_as_float(((unsigned int)h) << 16);
}

// branchless sorted-insert of key k into ascending top-3 (k0<=k1<=k2)
__device__ __forceinline__ void ins3(ull k, ull& k0, ull& k1, ull& k2) {
  ull t = k < k2 ? k : k2;
  ull u = k1 < t ? k1 : t;
  k2 = k1 < t ? t : k1;
  k1 = k0 < u ? u : k0;
  k0 = k0 < u ? k0 : u;
}

// ---------------------------------------------------------------------------
__global__ void cvt_bf16_kernel(const float* __restrict__ src, u16* __restrict__ dst, int n)
{
  int i = blockIdx.x * blockDim.x + threadIdx.x;
  if (i < n) dst[i] = f2bf(src[i]);
}

// ---------------------------------------------------------------------------
// transpose points_now [B][D2][S] -> pnT [B][S][D2]  (fp32, for knn gather)
// ---------------------------------------------------------------------------
__global__ __launch_bounds__(256) void transpose_kernel(
    const float* __restrict__ in, float* __restrict__ out)
{
  __shared__ float tile[32][33];
  const int b  = blockIdx.z;
  const int s0 = blockIdx.x * 32;
  const int d0 = blockIdx.y * 32;
  const int tx = threadIdx.x & 31, ty = threadIdx.x >> 5;

  const float* inb = in + ((size_t)b * D2_ + d0) * S_ + s0;
  #pragma unroll
  for (int r = 0; r < 4; ++r) {
    int d = r * 8 + ty;
    tile[d][tx] = inb[(size_t)d * S_ + tx];
  }
  __syncthreads();
  float* outb = out + ((size_t)b * S_ + s0) * D2_ + d0;
  #pragma unroll
  for (int r = 0; r < 4; ++r) {
    int s = r * 8 + ty;
    outb[(size_t)s * D2_ + tx] = tile[tx][s];
  }
}

// ---------------------------------------------------------------------------
// transpose+convert points_sa [B][D1][N] f32 -> psaT [B][N][D1] bf16
// ---------------------------------------------------------------------------
__global__ __launch_bounds__(256) void psaT_kernel(
    const float* __restrict__ in, u16* __restrict__ out)
{
  __shared__ float tile[32][33];
  const int b  = blockIdx.z;
  const int n0 = blockIdx.x * 32;
  const int d0 = blockIdx.y * 32;
  const int tx = threadIdx.x & 31, ty = threadIdx.x >> 5;

  const float* inb = in + ((size_t)b * D1_ + d0) * N_ + n0;
  #pragma unroll
  for (int r = 0; r < 4; ++r) {
    int d = r * 8 + ty;
    tile[d][tx] = inb[(size_t)d * N_ + tx];
  }
  __syncthreads();
  u16* outb = out + ((size_t)b * N_ + n0) * D1_ + d0;
  #pragma unroll
  for (int r = 0; r < 4; ++r) {
    int n = r * 8 + ty;
    outb[(size_t)n * D1_ + tx] = f2bf(tile[tx][n]);
  }
}

// ---------------------------------------------------------------------------
// K1: 3-NN + interpolation. 128 queries/block.
// ---------------------------------------------------------------------------
__global__ __launch_bounds__(256) void knn_interp_kernel(
    const float* __restrict__ xyz_sa, const float* __restrict__ xyz_now,
    const float* __restrict__ pnT, u16* __restrict__ interpT)
{
  __shared__ float4 sp[S_];
  __shared__ int   s_idx[128][3];
  __shared__ float s_w[128][3];

  const int b  = blockIdx.y;
  const int n0 = blockIdx.x * 128;

  const float* xb = xyz_now + (size_t)b * 3 * S_;
  for (int i = threadIdx.x; i < S_; i += 256) {
    float px = xb[i], py = xb[S_ + i], pz = xb[2 * S_ + i];
    sp[i] = make_float4(px, py, pz, px * px + py * py + pz * pz);
  }
  __syncthreads();

  const int qg = threadIdx.x >> 3;   // 0..31 query group (4 queries)
  const int t  = threadIdx.x & 7;    // scanner 0..7
  const int nb = n0 + qg * 4;

  const float* xq = xyz_sa + (size_t)b * 3 * N_;
  float qx[4], qy[4], qz[4], qq[4];
  #pragma unroll
  for (int w = 0; w < 4; ++w) {
    int n = nb + w;
    qx[w] = xq[n]; qy[w] = xq[N_ + n]; qz[w] = xq[2 * N_ + n];
    qq[w] = qx[w] * qx[w] + qy[w] * qy[w] + qz[w] * qz[w];
  }

  ull K0[4], K1[4], K2[4];
  #pragma unroll
  for (int w = 0; w < 4; ++w) { K0[w] = ~0ull; K1[w] = ~0ull; K2[w] = ~0ull; }

  #pragma unroll 2
  for (int it = 0; it < S_ / 8; ++it) {
    int s = (it << 3) | t;
    float4 p = sp[s];
    #pragma unroll
    for (int w = 0; w < 4; ++w) {
      float dot = qx[w] * p.x + qy[w] * p.y + qz[w] * p.z;
      float d = qq[w] - 2.0f * dot + p.w;
      unsigned int bits = __float_as_uint(d);
      unsigned int u = bits ^ (0x80000000u | (unsigned int)((int)bits >> 31));
      ull k = ((ull)u << 32) | (unsigned int)s;
      ins3(k, K0[w], K1[w], K2[w]);
    }
  }

  #pragma unroll
  for (int m = 1; m <= 4; m <<= 1) {
    #pragma unroll
    for (int w = 0; w < 4; ++w) {
      ull o0 = __shfl_xor(K0[w], m), o1 = __shfl_xor(K1[w], m), o2 = __shfl_xor(K2[w], m);
      ins3(o0, K0[w], K1[w], K2[w]);
      ins3(o1, K0[w], K1[w], K2[w]);
      ins3(o2, K0[w], K1[w], K2[w]);
    }
  }

  if (t == 0) {
    #pragma unroll
    for (int w = 0; w < 4; ++w) {
      unsigned int u0 = (unsigned int)(K0[w] >> 32);
      unsigned int u1 = (unsigned int)(K1[w] >> 32);
      unsigned int u2 = (unsigned int)(K2[w] >> 32);
      float d0 = __uint_as_float(u0 ^ (0x80000000u | ~(unsigned int)((int)u0 >> 31)));
      float d1 = __uint_as_float(u1 ^ (0x80000000u | ~(unsigned int)((int)u1 >> 31)));
      float d2 = __uint_as_float(u2 ^ (0x80000000u | ~(unsigned int)((int)u2 >> 31)));
      float r0 = 1.0f / (d0 + 1e-8f);
      float r1 = 1.0f / (d1 + 1e-8f);
      float r2 = 1.0f / (d2 + 1e-8f);
      float rs = 1.0f / (r0 + r1 + r2);
      int qi = qg * 4 + w;
      s_idx[qi][0] = (int)(K0[w] & 0xFFFFFFFFu);
      s_idx[qi][1] = (int)(K1[w] & 0xFFFFFFFFu);
      s_idx[qi][2] = (int)(K2[w] & 0xFFFFFFFFu);
      s_w[qi][0] = r0 * rs; s_w[qi][1] = r1 * rs; s_w[qi][2] = r2 * rs;
    }
  }
  __syncthreads();

  const int wave = threadIdx.x >> 6;
  const int lane = threadIdx.x & 63;
  const float* pb = pnT + (size_t)b * S_ * D2_;
  u16* ob = interpT + ((size_t)b * N_ + n0) * D2_;
  #pragma unroll 2
  for (int i = 0; i < 32; ++i) {
    const int qi = wave * 32 + i;
    const int j0 = s_idx[qi][0], j1 = s_idx[qi][1], j2 = s_idx[qi][2];
    const float w0 = s_w[qi][0], w1 = s_w[qi][1], w2 = s_w[qi][2];
    float4 f0 = *(const float4*)(pb + (size_t)j0 * D2_ + lane * 4);
    float4 f1 = *(const float4*)(pb + (size_t)j1 * D2_ + lane * 4);
    float4 f2 = *(const float4*)(pb + (size_t)j2 * D2_ + lane * 4);
    float rx = w0 * f0.x + w1 * f1.x + w2 * f2.x;
    float ry = w0 * f0.y + w1 * f1.y + w2 * f2.y;
    float rz = w0 * f0.z + w1 * f1.z + w2 * f2.z;
    float rw = w0 * f0.w + w1 * f1.w + w2 * f2.w;
    unsigned int lo = (unsigned int)f2bf(rx) | ((unsigned int)f2bf(ry) << 16);
    unsigned int hi = (unsigned int)f2bf(rz) | ((unsigned int)f2bf(rw) << 16);
    *(uint2*)(ob + (size_t)qi * D2_ + lane * 4) = make_uint2(lo, hi);
  }
}

// ---------------------------------------------------------------------------
// GEMM1 (MFMA bf16, double-buffered reg-prefetch pipeline + LDS-staged
// coalesced epilogue): y0b[b,n,o] = W0[o,:] . x[b,:,n] + b0[o]; + stats.
// ---------------------------------------------------------------------------
union SM1 {
  struct { u16 As[2][128][40]; u16 Bs[2][128][40]; } p;
  u16 stage[128][136];   // epilogue transpose tile (row stride 272B, 16B-mult)
};

__global__ __launch_bounds__(256, 4) void gemm1_mfma_kernel(
    const u16* __restrict__ psaT, const u16* __restrict__ interpT,
    const u16* __restrict__ W0b, const float* __restrict__ b0,
    u16* __restrict__ y0b, float* __restrict__ stats)
{
  __shared__ SM1 sm;
  u16 (&As)[2][128][40] = sm.p.As;
  u16 (&Bs)[2][128][40] = sm.p.Bs;

  const int bz = blockIdx.z;
  const int n0 = blockIdx.x * 128;
  const int o0 = blockIdx.y * 128;
  const int tid = threadIdx.x;
  const int wid = tid >> 6, lane = tid & 63;
  const int wo = wid & 1, wn = wid >> 1;
  const int m = lane & 15, g = lane >> 4;
  const int r0 = tid >> 2, cb = (tid & 3) << 3;  // staging row (h=0), k-chunk

  f32x4 acc[4][4];
  #pragma unroll
  for (int i = 0; i < 4; ++i)
    #pragma unroll
    for (int j = 0; j < 4; ++j) acc[i][j] = (f32x4){0.f, 0.f, 0.f, 0.f};

  uint4 ra[2], rb[2];

  auto gload = [&](int kt) {
    #pragma unroll
    for (int h = 0; h < 2; ++h) {
      const int row = r0 + h * 64;
      ra[h] = *(const uint4*)(W0b + (size_t)(o0 + row) * C0_ + kt + cb);
      const u16* bsrc = (kt < D1_)
          ? psaT    + (size_t)(bz * N_ + n0 + row) * D1_ + kt + cb
          : interpT + (size_t)(bz * N_ + n0 + row) * D2_ + (kt - D1_) + cb;
      rb[h] = *(const uint4*)bsrc;
    }
  };
  auto sstore = [&](int buf) {
    #pragma unroll
    for (int h = 0; h < 2; ++h) {
      const int row = r0 + h * 64;
      *(uint4*)&As[buf][row][cb] = ra[h];
      *(uint4*)&Bs[buf][row][cb] = rb[h];
    }
  };

  gload(0);
  sstore(0);
  __syncthreads();

  for (int kt = 0; kt < 12; ++kt) {
    const int cur = kt & 1;
    if (kt < 11) gload((kt + 1) << 5);   // issue early: overlaps MFMA below

    bf16x8 af[4], bfv[4];
    #pragma unroll
    for (int f = 0; f < 4; ++f)
      af[f] = __builtin_bit_cast(bf16x8, *(const short8_*)&As[cur][wo * 64 + f * 16 + m][g * 8]);
    #pragma unroll
    for (int f = 0; f < 4; ++f)
      bfv[f] = __builtin_bit_cast(bf16x8, *(const short8_*)&Bs[cur][wn * 64 + f * 16 + m][g * 8]);
    #pragma unroll
    for (int i = 0; i < 4; ++i)
      #pragma unroll
      for (int j = 0; j < 4; ++j)
        acc[i][j] = __builtin_amdgcn_mfma_f32_16x16x32_bf16(af[i], bfv[j], acc[i][j], 0, 0, 0);

    if (kt < 11) sstore(cur ^ 1);        // write late (after MFMA issues)
    __syncthreads();
  }

  // epilogue: bias + stats, stage bf16 tile [n_local][o_local] in LDS
  #pragma unroll
  for (int of = 0; of < 4; ++of) {
    const int ol = wo * 64 + of * 16 + g * 4;   // o within 128-tile
    const int ob = o0 + ol;
    float bias[4], s1[4], s2[4];
    #pragma unroll
    for (int r = 0; r < 4; ++r) { bias[r] = b0[ob + r]; s1[r] = 0.f; s2[r] = 0.f; }
    #pragma unroll
    for (int nf = 0; nf < 4; ++nf) {
      const int nl = wn * 64 + nf * 16 + m;
      float y[4];
      #pragma unroll
      for (int r = 0; r < 4; ++r) {
        y[r] = acc[of][nf][r] + bias[r];
        s1[r] += y[r]; s2[r] += y[r] * y[r];
      }
      unsigned int lo = (unsigned int)f2bf(y[0]) | ((unsigned int)f2bf(y[1]) << 16);
      unsigned int hi = (unsigned int)f2bf(y[2]) | ((unsigned int)f2bf(y[3]) << 16);
      *(uint2*)&sm.stage[nl][ol] = make_uint2(lo, hi);
    }
    #pragma unroll
    for (int mk = 1; mk < 16; mk <<= 1)
      #pragma unroll
      for (int r = 0; r < 4; ++r) {
        s1[r] += __shfl_xor(s1[r], mk);
        s2[r] += __shfl_xor(s2[r], mk);
      }
    if (m == 0) {
      #pragma unroll
      for (int r = 0; r < 4; ++r) {
        atomicAdd(&stats[ob + r], s1[r]);
        atomicAdd(&stats[C1_ + ob + r], s2[r]);
      }
    }
  }
  __syncthreads();

  // coalesced write: 16 threads per row -> 256B contiguous segments
  {
    const int rrow = tid >> 4;          // 0..15
    const int col  = (tid & 15) * 8;    // u16 units, 0..120
    #pragma unroll
    for (int pass = 0; pass < 8; ++pass) {
      const int r = pass * 16 + rrow;
      uint4 v = *(const uint4*)&sm.stage[r][col];
      *(uint4*)(y0b + (size_t)(bz * N_ + n0 + r) * C1_ + o0 + col) = v;
    }
  }
}

// ---------------------------------------------------------------------------
// GEMM2 (MFMA bf16, same pipeline): y1b[b,p,n] = W1 . relu(bn0(y0)) + b1 (bf16 out)
// BN0+ReLU folded into the staging store; coef cached in LDS.
// ---------------------------------------------------------------------------
__global__ __launch_bounds__(256, 4) void gemm2_mfma_kernel(
    const u16* __restrict__ y0b, const float* __restrict__ coef,
    const u16* __restrict__ W1b, const float* __restrict__ b1,
    u16* __restrict__ y1b, float* __restrict__ stats)
{
  __shared__ u16 As[2][128][40];
  __shared__ u16 Bs[2][128][40];
  __shared__ float cfa[C1_], cfc[C1_];

  const int bz = blockIdx.z;
  const int n0 = blockIdx.x * 128;
  const int tid = threadIdx.x;
  const int wid = tid >> 6, lane = tid & 63;
  const int wo = wid & 1, wn = wid >> 1;
  const int m = lane & 15, g = lane >> 4;
  const int r0 = tid >> 2, cb = (tid & 3) << 3;

  f32x4 acc[4][4];
  #pragma unroll
  for (int i = 0; i < 4; ++i)
    #pragma unroll
    for (int j = 0; j < 4; ++j) acc[i][j] = (f32x4){0.f, 0.f, 0.f, 0.f};

  cfa[tid] = coef[tid];
  cfc[tid] = coef[C1_ + tid];

  uint4 ra[2], rb[2];
  int kst = 0;

  auto gload = [&](int kt) {
    kst = kt;
    #pragma unroll
    for (int h = 0; h < 2; ++h) {
      const int row = r0 + h * 64;
      ra[h] = *(const uint4*)(W1b + (size_t)row * C1_ + kt + cb);
      rb[h] = *(const uint4*)(y0b + (size_t)(bz * N_ + n0 + row) * C1_ + kt + cb);
    }
  };
  auto sstore = [&](int buf) {
    const int cg = kst + cb;
    #pragma unroll
    for (int h = 0; h < 2; ++h) {
      const int row = r0 + h * 64;
      *(uint4*)&As[buf][row][cb] = ra[h];
      uint4 v = rb[h];
      float f0 = fmaxf(0.f, fmaf(bf2f((u16)(v.x & 0xffff)), cfa[cg + 0], cfc[cg + 0]));
      float f1 = fmaxf(0.f, fmaf(bf2f((u16)(v.x >> 16)),    cfa[cg + 1], cfc[cg + 1]));
      float f2 = fmaxf(0.f, fmaf(bf2f((u16)(v.y & 0xffff)), cfa[cg + 2], cfc[cg + 2]));
      float f3 = fmaxf(0.f, fmaf(bf2f((u16)(v.y >> 16)),    cfa[cg + 3], cfc[cg + 3]));
      float f4 = fmaxf(0.f, fmaf(bf2f((u16)(v.z & 0xffff)), cfa[cg + 4], cfc[cg + 4]));
      float f5 = fmaxf(0.f, fmaf(bf2f((u16)(v.z >> 16)),    cfa[cg + 5], cfc[cg + 5]));
      float f6 = fmaxf(0.f, fmaf(bf2f((u16)(v.w & 0xffff)), cfa[cg + 6], cfc[cg + 6]));
      float f7 = fmaxf(0.f, fmaf(bf2f((u16)(v.w >> 16)),    cfa[cg + 7], cfc[cg + 7]));
      uint4 o;
      o.x = (unsigned int)f2bf(f0) | ((unsigned int)f2bf(f1) << 16);
      o.y = (unsigned int)f2bf(f2) | ((unsigned int)f2bf(f3) << 16);
      o.z = (unsigned int)f2bf(f4) | ((unsigned int)f2bf(f5) << 16);
      o.w = (unsigned int)f2bf(f6) | ((unsigned int)f2bf(f7) << 16);
      *(uint4*)&Bs[buf][row][cb] = o;
    }
  };

  gload(0);
  __syncthreads();     // cfa/cfc ready
  sstore(0);
  __syncthreads();

  for (int kt = 0; kt < 8; ++kt) {
    const int cur = kt & 1;
    if (kt < 7) gload((kt + 1) << 5);

    bf16x8 af[4], bfv[4];
    #pragma unroll
    for (int f = 0; f < 4; ++f)
      af[f] = __builtin_bit_cast(bf16x8, *(const short8_*)&As[cur][wo * 64 + f * 16 + m][g * 8]);
    #pragma unroll
    for (int f = 0; f < 4; ++f)
      bfv[f] = __builtin_bit_cast(bf16x8, *(const short8_*)&Bs[cur][wn * 64 + f * 16 + m][g * 8]);
    #pragma unroll
    for (int i = 0; i < 4; ++i)
      #pragma unroll
      for (int j = 0; j < 4; ++j)
        acc[i][j] = __builtin_amdgcn_mfma_f32_16x16x32_bf16(af[i], bfv[j], acc[i][j], 0, 0, 0);

    if (kt < 7) sstore(cur ^ 1);
    __syncthreads();
  }

  #pragma unroll
  for (int of = 0; of < 4; ++of) {
    const int pb = wo * 64 + of * 16 + g * 4;
    float bias[4], s1[4], s2[4];
    #pragma unroll
    for (int r = 0; r < 4; ++r) { bias[r] = b1[pb + r]; s1[r] = 0.f; s2[r] = 0.f; }
    #pragma unroll
    for (int nf = 0; nf < 4; ++nf) {
      const int n = n0 + wn * 64 + nf * 16 + m;
      #pragma unroll
      for (int r = 0; r < 4; ++r) {
        float y = acc[of][nf][r] + bias[r];
        s1[r] += y; s2[r] += y * y;
        y1b[((size_t)bz * C2_ + pb + r) * N_ + n] = f2bf(y);
      }
    }
    #pragma unroll
    for (int mk = 1; mk < 16; mk <<= 1)
      #pragma unroll
      for (int r = 0; r < 4; ++r) {
        s1[r] += __shfl_xor(s1[r], mk);
        s2[r] += __shfl_xor(s2[r], mk);
      }
    if (m == 0) {
      #pragma unroll
      for (int r = 0; r < 4; ++r) {
        atomicAdd(&stats[pb + r], s1[r]);
        atomicAdd(&stats[C2_ + pb + r], s2[r]);
      }
    }
  }
}

// ---------------------------------------------------------------------------
__global__ void bn_coef_kernel(const float* __restrict__ g, const float* __restrict__ be,
                               const float* __restrict__ stats, float* __restrict__ coef,
                               int C)
{
  int o = threadIdx.x;
  if (o < C) {
    const float invM = 1.0f / 65536.0f;   // B*N
    float mean = stats[o] * invM;
    float var  = stats[C + o] * invM - mean * mean;
    float a = g[o] / sqrtf(var + BN_EPS);
    float c = be[o] - mean * a;
    coef[o] = a;
    coef[C + o] = c;
  }
}

__global__ void zero_kernel(float* __restrict__ p, int n)
{
  int i = blockIdx.x * blockDim.x + threadIdx.x;
  if (i < n) p[i] = 0.0f;
}

// ---------------------------------------------------------------------------
// final: BN1 + ReLU elementwise, bf16 in -> fp32 out
// ---------------------------------------------------------------------------
__global__ __launch_bounds__(256) void final_kernel(
    const u16* __restrict__ y1b, const float* __restrict__ cf, float* __restrict__ out)
{
  const size_t total4 = (size_t)B_ * C2_ * N_ / 4;
  const size_t stride = (size_t)gridDim.x * blockDim.x;
  for (size_t f = (size_t)blockIdx.x * blockDim.x + threadIdx.x; f < total4; f += stride) {
    size_t base = f * 4;
    int p = (int)((base >> 13) & (C2_ - 1));
    float a = cf[p], c = cf[C2_ + p];
    uint2 v = *(const uint2*)(y1b + base);
    float4 r;
    r.x = fmaxf(0.0f, fmaf(bf2f((u16)(v.x & 0xffff)), a, c));
    r.y = fmaxf(0.0f, fmaf(bf2f((u16)(v.x >> 16)),    a, c));
    r.z = fmaxf(0.0f, fmaf(bf2f((u16)(v.y & 0xffff)), a, c));
    r.w = fmaxf(0.0f, fmaf(bf2f((u16)(v.y >> 16)),    a, c));
    *(float4*)(out + base) = r;
  }
}

// ---------------------------------------------------------------------------
extern "C" void kernel_launch(void* const* d_in, const int* in_sizes, int n_in,
                              void* d_out, int out_size, void* d_ws, size_t ws_size,
                              hipStream_t stream)
{
  const float* xyz_sa     = (const float*)d_in[0];
  const float* xyz_now    = (const float*)d_in[1];
  const float* points_sa  = (const float*)d_in[2];
  const float* points_now = (const float*)d_in[3];
  const float* W0  = (const float*)d_in[4];
  const float* b0  = (const float*)d_in[5];
  const float* g0  = (const float*)d_in[6];
  const float* be0 = (const float*)d_in[7];
  const float* W1  = (const float*)d_in[8];
  const float* b1  = (const float*)d_in[9];
  const float* g1  = (const float*)d_in[10];
  const float* be1 = (const float*)d_in[11];

  const size_t MB = 1048576ull;
  char* base = (char*)d_ws;
  u16*   interpT = (u16*)(base + 0);          // [B][N][256] bf16  32MB
  u16*   psaT    = (u16*)(base + 32 * MB);    // [B][N][128] bf16  16MB
  float* pnT     = (float*)(base + 48 * MB);  // [B][S][256] f32   16MB (dead after knn)
  u16*   y1b     = (u16*)(base + 48 * MB);    // [B][C2][N] bf16   16MB (overlays pnT)
  u16*   y0b     = (u16*)(base + 64 * MB);    // [B][N][256] bf16  32MB
  u16*   W0b     = (u16*)(base + 96 * MB);    // 98304 bf16
  u16*   W1b     = (u16*)(base + 96 * MB + 512 * 1024); // 32768 bf16
  float* stats   = (float*)(base + 97 * MB);  // 768 f
  float* coef    = stats + 768;               // 768 f
  float* out     = (float*)d_out;

  hipLaunchKernelGGL(zero_kernel, dim3(1), dim3(768), 0, stream, stats, 768);
  hipLaunchKernelGGL(cvt_bf16_kernel, dim3((C1_ * C0_ + 255) / 256), dim3(256), 0, stream,
                     W0, W0b, C1_ * C0_);
  hipLaunchKernelGGL(cvt_bf16_kernel, dim3((C2_ * C1_ + 255) / 256), dim3(256), 0, stream,
                     W1, W1b, C2_ * C1_);
  hipLaunchKernelGGL(transpose_kernel, dim3(S_ / 32, D2_ / 32, B_), dim3(256), 0, stream,
                     points_now, pnT);
  hipLaunchKernelGGL(psaT_kernel, dim3(N_ / 32, D1_ / 32, B_), dim3(256), 0, stream,
                     points_sa, psaT);
  hipLaunchKernelGGL(knn_interp_kernel, dim3(N_ / 128, B_), dim3(256), 0, stream,
                     xyz_sa, xyz_now, pnT, interpT);
  hipLaunchKernelGGL(gemm1_mfma_kernel, dim3(N_ / 128, 2, B_), dim3(256), 0, stream,
                     psaT, interpT, W0b, b0, y0b, stats);
  hipLaunchKernelGGL(bn_coef_kernel, dim3(1), dim3(256), 0, stream,
                     g0, be0, stats, coef, C1_);
  hipLaunchKernelGGL(gemm2_mfma_kernel, dim3(N_ / 128, 1, B_), dim3(256), 0, stream,
                     y0b, coef, W1b, b1, y1b, stats + 512);
  hipLaunchKernelGGL(bn_coef_kernel, dim3(1), dim3(128), 0, stream,
                     g1, be1, stats + 512, coef + 512, C2_);
  hipLaunchKernelGGL(final_kernel, dim3(2048), dim3(256), 0, stream,
                     y1b, coef + 512, out);
}

// Round 7
// 393.988 us; speedup vs baseline: 1.0172x; 1.0172x over previous
//
#include <hip/hip_runtime.h>

#define B_ 8
#define N_ 8192
#define S_ 2048
#define D1_ 128
#define D2_ 256
#define C0_ 384
#define C1_ 256
#define C2_ 128
#define BN_EPS 1e-5f

typedef unsigned long long ull;
typedef unsigned short u16;
typedef __bf16 bf16x8 __attribute__((ext_vector_type(8)));
typedef float f32x4 __attribute__((ext_vector_type(4)));
typedef short short8_ __attribute__((ext_vector_type(8)));

__device__ __forceinline__ u16 f2bf(float x) {
  unsigned int u = __float_as_uint(x);
  unsigned int r = u + 0x7fffu + ((u >> 16) & 1u);
  return (u16)(r >> 16);
}
__device__ __forceinline__ float bf2f(u16 h) {
  return __uint_as_float(((unsigned int)h) << 16);
}

// branchless sorted-insert of key k into ascending top-3 (k0<=k1<=k2)
__device__ __forceinline__ void ins3(ull k, ull& k0, ull& k1, ull& k2) {
  ull t = k < k2 ? k : k2;
  ull u = k1 < t ? k1 : t;
  k2 = k1 < t ? t : k1;
  k1 = k0 < u ? u : k0;
  k0 = k0 < u ? k0 : u;
}

// ---------------------------------------------------------------------------
__global__ void cvt_bf16_kernel(const float* __restrict__ src, u16* __restrict__ dst, int n)
{
  int i = blockIdx.x * blockDim.x + threadIdx.x;
  if (i < n) dst[i] = f2bf(src[i]);
}

// ---------------------------------------------------------------------------
// transpose points_now [B][D2][S] -> pnT [B][S][D2]  (fp32, for knn gather)
// ---------------------------------------------------------------------------
__global__ __launch_bounds__(256) void transpose_kernel(
    const float* __restrict__ in, float* __restrict__ out)
{
  __shared__ float tile[32][33];
  const int b  = blockIdx.z;
  const int s0 = blockIdx.x * 32;
  const int d0 = blockIdx.y * 32;
  const int tx = threadIdx.x & 31, ty = threadIdx.x >> 5;

  const float* inb = in + ((size_t)b * D2_ + d0) * S_ + s0;
  #pragma unroll
  for (int r = 0; r < 4; ++r) {
    int d = r * 8 + ty;
    tile[d][tx] = inb[(size_t)d * S_ + tx];
  }
  __syncthreads();
  float* outb = out + ((size_t)b * S_ + s0) * D2_ + d0;
  #pragma unroll
  for (int r = 0; r < 4; ++r) {
    int s = r * 8 + ty;
    outb[(size_t)s * D2_ + tx] = tile[tx][s];
  }
}

// ---------------------------------------------------------------------------
// transpose+convert points_sa [B][D1][N] f32 -> psaT [B][N][D1] bf16
// ---------------------------------------------------------------------------
__global__ __launch_bounds__(256) void psaT_kernel(
    const float* __restrict__ in, u16* __restrict__ out)
{
  __shared__ float tile[32][33];
  const int b  = blockIdx.z;
  const int n0 = blockIdx.x * 32;
  const int d0 = blockIdx.y * 32;
  const int tx = threadIdx.x & 31, ty = threadIdx.x >> 5;

  const float* inb = in + ((size_t)b * D1_ + d0) * N_ + n0;
  #pragma unroll
  for (int r = 0; r < 4; ++r) {
    int d = r * 8 + ty;
    tile[d][tx] = inb[(size_t)d * N_ + tx];
  }
  __syncthreads();
  u16* outb = out + ((size_t)b * N_ + n0) * D1_ + d0;
  #pragma unroll
  for (int r = 0; r < 4; ++r) {
    int n = r * 8 + ty;
    outb[(size_t)n * D1_ + tx] = f2bf(tile[tx][n]);
  }
}

// ---------------------------------------------------------------------------
// K1: 3-NN + interpolation. 128 queries/block.
// ---------------------------------------------------------------------------
__global__ __launch_bounds__(256) void knn_interp_kernel(
    const float* __restrict__ xyz_sa, const float* __restrict__ xyz_now,
    const float* __restrict__ pnT, u16* __restrict__ interpT)
{
  __shared__ float4 sp[S_];
  __shared__ int   s_idx[128][3];
  __shared__ float s_w[128][3];

  const int b  = blockIdx.y;
  const int n0 = blockIdx.x * 128;

  const float* xb = xyz_now + (size_t)b * 3 * S_;
  for (int i = threadIdx.x; i < S_; i += 256) {
    float px = xb[i], py = xb[S_ + i], pz = xb[2 * S_ + i];
    sp[i] = make_float4(px, py, pz, px * px + py * py + pz * pz);
  }
  __syncthreads();

  const int qg = threadIdx.x >> 3;   // 0..31 query group (4 queries)
  const int t  = threadIdx.x & 7;    // scanner 0..7
  const int nb = n0 + qg * 4;

  const float* xq = xyz_sa + (size_t)b * 3 * N_;
  float qx[4], qy[4], qz[4], qq[4];
  #pragma unroll
  for (int w = 0; w < 4; ++w) {
    int n = nb + w;
    qx[w] = xq[n]; qy[w] = xq[N_ + n]; qz[w] = xq[2 * N_ + n];
    qq[w] = qx[w] * qx[w] + qy[w] * qy[w] + qz[w] * qz[w];
  }

  ull K0[4], K1[4], K2[4];
  #pragma unroll
  for (int w = 0; w < 4; ++w) { K0[w] = ~0ull; K1[w] = ~0ull; K2[w] = ~0ull; }

  #pragma unroll 2
  for (int it = 0; it < S_ / 8; ++it) {
    int s = (it << 3) | t;
    float4 p = sp[s];
    #pragma unroll
    for (int w = 0; w < 4; ++w) {
      float dot = qx[w] * p.x + qy[w] * p.y + qz[w] * p.z;
      float d = qq[w] - 2.0f * dot + p.w;
      unsigned int bits = __float_as_uint(d);
      unsigned int u = bits ^ (0x80000000u | (unsigned int)((int)bits >> 31));
      ull k = ((ull)u << 32) | (unsigned int)s;
      ins3(k, K0[w], K1[w], K2[w]);
    }
  }

  #pragma unroll
  for (int m = 1; m <= 4; m <<= 1) {
    #pragma unroll
    for (int w = 0; w < 4; ++w) {
      ull o0 = __shfl_xor(K0[w], m), o1 = __shfl_xor(K1[w], m), o2 = __shfl_xor(K2[w], m);
      ins3(o0, K0[w], K1[w], K2[w]);
      ins3(o1, K0[w], K1[w], K2[w]);
      ins3(o2, K0[w], K1[w], K2[w]);
    }
  }

  if (t == 0) {
    #pragma unroll
    for (int w = 0; w < 4; ++w) {
      unsigned int u0 = (unsigned int)(K0[w] >> 32);
      unsigned int u1 = (unsigned int)(K1[w] >> 32);
      unsigned int u2 = (unsigned int)(K2[w] >> 32);
      float d0 = __uint_as_float(u0 ^ (0x80000000u | ~(unsigned int)((int)u0 >> 31)));
      float d1 = __uint_as_float(u1 ^ (0x80000000u | ~(unsigned int)((int)u1 >> 31)));
      float d2 = __uint_as_float(u2 ^ (0x80000000u | ~(unsigned int)((int)u2 >> 31)));
      float r0 = 1.0f / (d0 + 1e-8f);
      float r1 = 1.0f / (d1 + 1e-8f);
      float r2 = 1.0f / (d2 + 1e-8f);
      float rs = 1.0f / (r0 + r1 + r2);
      int qi = qg * 4 + w;
      s_idx[qi][0] = (int)(K0[w] & 0xFFFFFFFFu);
      s_idx[qi][1] = (int)(K1[w] & 0xFFFFFFFFu);
      s_idx[qi][2] = (int)(K2[w] & 0xFFFFFFFFu);
      s_w[qi][0] = r0 * rs; s_w[qi][1] = r1 * rs; s_w[qi][2] = r2 * rs;
    }
  }
  __syncthreads();

  const int wave = threadIdx.x >> 6;
  const int lane = threadIdx.x & 63;
  const float* pb = pnT + (size_t)b * S_ * D2_;
  u16* ob = interpT + ((size_t)b * N_ + n0) * D2_;
  #pragma unroll 2
  for (int i = 0; i < 32; ++i) {
    const int qi = wave * 32 + i;
    const int j0 = s_idx[qi][0], j1 = s_idx[qi][1], j2 = s_idx[qi][2];
    const float w0 = s_w[qi][0], w1 = s_w[qi][1], w2 = s_w[qi][2];
    float4 f0 = *(const float4*)(pb + (size_t)j0 * D2_ + lane * 4);
    float4 f1 = *(const float4*)(pb + (size_t)j1 * D2_ + lane * 4);
    float4 f2 = *(const float4*)(pb + (size_t)j2 * D2_ + lane * 4);
    float rx = w0 * f0.x + w1 * f1.x + w2 * f2.x;
    float ry = w0 * f0.y + w1 * f1.y + w2 * f2.y;
    float rz = w0 * f0.z + w1 * f1.z + w2 * f2.z;
    float rw = w0 * f0.w + w1 * f1.w + w2 * f2.w;
    unsigned int lo = (unsigned int)f2bf(rx) | ((unsigned int)f2bf(ry) << 16);
    unsigned int hi = (unsigned int)f2bf(rz) | ((unsigned int)f2bf(rw) << 16);
    *(uint2*)(ob + (size_t)qi * D2_ + lane * 4) = make_uint2(lo, hi);
  }
}

// ---------------------------------------------------------------------------
// GEMM1 (MFMA bf16, double-buffered reg-prefetch pipeline + LDS-staged
// coalesced epilogue): y0b[b,n,o] = W0[o,:] . x[b,:,n] + b0[o]; + stats.
// launch_bounds(256,2): prefetch regs must NOT spill (round-6 lesson:
// (256,4) capped arch-VGPRs at 64 -> 110MB/dispatch scratch traffic).
// ---------------------------------------------------------------------------
union SM1 {
  struct { u16 As[2][128][40]; u16 Bs[2][128][40]; } p;
  u16 stage[128][136];   // epilogue transpose tile (row stride 272B, 16B-mult)
};

__global__ __launch_bounds__(256, 2) void gemm1_mfma_kernel(
    const u16* __restrict__ psaT, const u16* __restrict__ interpT,
    const u16* __restrict__ W0b, const float* __restrict__ b0,
    u16* __restrict__ y0b, float* __restrict__ stats)
{
  __shared__ SM1 sm;
  u16 (&As)[2][128][40] = sm.p.As;
  u16 (&Bs)[2][128][40] = sm.p.Bs;

  const int bz = blockIdx.z;
  const int n0 = blockIdx.x * 128;
  const int o0 = blockIdx.y * 128;
  const int tid = threadIdx.x;
  const int wid = tid >> 6, lane = tid & 63;
  const int wo = wid & 1, wn = wid >> 1;
  const int m = lane & 15, g = lane >> 4;
  const int r0 = tid >> 2, cb = (tid & 3) << 3;  // staging row (h=0), k-chunk

  f32x4 acc[4][4];
  #pragma unroll
  for (int i = 0; i < 4; ++i)
    #pragma unroll
    for (int j = 0; j < 4; ++j) acc[i][j] = (f32x4){0.f, 0.f, 0.f, 0.f};

  uint4 ra[2], rb[2];

  auto gload = [&](int kt) {
    #pragma unroll
    for (int h = 0; h < 2; ++h) {
      const int row = r0 + h * 64;
      ra[h] = *(const uint4*)(W0b + (size_t)(o0 + row) * C0_ + kt + cb);
      const u16* bsrc = (kt < D1_)
          ? psaT    + (size_t)(bz * N_ + n0 + row) * D1_ + kt + cb
          : interpT + (size_t)(bz * N_ + n0 + row) * D2_ + (kt - D1_) + cb;
      rb[h] = *(const uint4*)bsrc;
    }
  };
  auto sstore = [&](int buf) {
    #pragma unroll
    for (int h = 0; h < 2; ++h) {
      const int row = r0 + h * 64;
      *(uint4*)&As[buf][row][cb] = ra[h];
      *(uint4*)&Bs[buf][row][cb] = rb[h];
    }
  };

  gload(0);
  sstore(0);
  __syncthreads();

  for (int kt = 0; kt < 12; ++kt) {
    const int cur = kt & 1;
    if (kt < 11) gload((kt + 1) << 5);   // issue early: overlaps MFMA below

    bf16x8 af[4], bfv[4];
    #pragma unroll
    for (int f = 0; f < 4; ++f)
      af[f] = __builtin_bit_cast(bf16x8, *(const short8_*)&As[cur][wo * 64 + f * 16 + m][g * 8]);
    #pragma unroll
    for (int f = 0; f < 4; ++f)
      bfv[f] = __builtin_bit_cast(bf16x8, *(const short8_*)&Bs[cur][wn * 64 + f * 16 + m][g * 8]);
    #pragma unroll
    for (int i = 0; i < 4; ++i)
      #pragma unroll
      for (int j = 0; j < 4; ++j)
        acc[i][j] = __builtin_amdgcn_mfma_f32_16x16x32_bf16(af[i], bfv[j], acc[i][j], 0, 0, 0);

    if (kt < 11) sstore(cur ^ 1);        // write late (after MFMA issues)
    __syncthreads();
  }

  // epilogue: bias + stats, stage bf16 tile [n_local][o_local] in LDS
  #pragma unroll
  for (int of = 0; of < 4; ++of) {
    const int ol = wo * 64 + of * 16 + g * 4;   // o within 128-tile
    const int ob = o0 + ol;
    float bias[4], s1[4], s2[4];
    #pragma unroll
    for (int r = 0; r < 4; ++r) { bias[r] = b0[ob + r]; s1[r] = 0.f; s2[r] = 0.f; }
    #pragma unroll
    for (int nf = 0; nf < 4; ++nf) {
      const int nl = wn * 64 + nf * 16 + m;
      float y[4];
      #pragma unroll
      for (int r = 0; r < 4; ++r) {
        y[r] = acc[of][nf][r] + bias[r];
        s1[r] += y[r]; s2[r] += y[r] * y[r];
      }
      unsigned int lo = (unsigned int)f2bf(y[0]) | ((unsigned int)f2bf(y[1]) << 16);
      unsigned int hi = (unsigned int)f2bf(y[2]) | ((unsigned int)f2bf(y[3]) << 16);
      *(uint2*)&sm.stage[nl][ol] = make_uint2(lo, hi);
    }
    #pragma unroll
    for (int mk = 1; mk < 16; mk <<= 1)
      #pragma unroll
      for (int r = 0; r < 4; ++r) {
        s1[r] += __shfl_xor(s1[r], mk);
        s2[r] += __shfl_xor(s2[r], mk);
      }
    if (m == 0) {
      #pragma unroll
      for (int r = 0; r < 4; ++r) {
        atomicAdd(&stats[ob + r], s1[r]);
        atomicAdd(&stats[C1_ + ob + r], s2[r]);
      }
    }
  }
  __syncthreads();

  // coalesced write: 16 threads per row -> 256B contiguous segments
  {
    const int rrow = tid >> 4;          // 0..15
    const int col  = (tid & 15) * 8;    // u16 units, 0..120
    #pragma unroll
    for (int pass = 0; pass < 8; ++pass) {
      const int r = pass * 16 + rrow;
      uint4 v = *(const uint4*)&sm.stage[r][col];
      *(uint4*)(y0b + (size_t)(bz * N_ + n0 + r) * C1_ + o0 + col) = v;
    }
  }
}

// ---------------------------------------------------------------------------
// GEMM2 (MFMA bf16, same pipeline): y1b[b,p,n] = W1 . relu(bn0(y0)) + b1 (bf16 out)
// BN0+ReLU folded into the staging store; coef cached in LDS.
// ---------------------------------------------------------------------------
__global__ __launch_bounds__(256, 2) void gemm2_mfma_kernel(
    const u16* __restrict__ y0b, const float* __restrict__ coef,
    const u16* __restrict__ W1b, const float* __restrict__ b1,
    u16* __restrict__ y1b, float* __restrict__ stats)
{
  __shared__ u16 As[2][128][40];
  __shared__ u16 Bs[2][128][40];
  __shared__ float cfa[C1_], cfc[C1_];

  const int bz = blockIdx.z;
  const int n0 = blockIdx.x * 128;
  const int tid = threadIdx.x;
  const int wid = tid >> 6, lane = tid & 63;
  const int wo = wid & 1, wn = wid >> 1;
  const int m = lane & 15, g = lane >> 4;
  const int r0 = tid >> 2, cb = (tid & 3) << 3;

  f32x4 acc[4][4];
  #pragma unroll
  for (int i = 0; i < 4; ++i)
    #pragma unroll
    for (int j = 0; j < 4; ++j) acc[i][j] = (f32x4){0.f, 0.f, 0.f, 0.f};

  cfa[tid] = coef[tid];
  cfc[tid] = coef[C1_ + tid];

  uint4 ra[2], rb[2];
  int kst = 0;

  auto gload = [&](int kt) {
    kst = kt;
    #pragma unroll
    for (int h = 0; h < 2; ++h) {
      const int row = r0 + h * 64;
      ra[h] = *(const uint4*)(W1b + (size_t)row * C1_ + kt + cb);
      rb[h] = *(const uint4*)(y0b + (size_t)(bz * N_ + n0 + row) * C1_ + kt + cb);
    }
  };
  auto sstore = [&](int buf) {
    const int cg = kst + cb;
    #pragma unroll
    for (int h = 0; h < 2; ++h) {
      const int row = r0 + h * 64;
      *(uint4*)&As[buf][row][cb] = ra[h];
      uint4 v = rb[h];
      float f0 = fmaxf(0.f, fmaf(bf2f((u16)(v.x & 0xffff)), cfa[cg + 0], cfc[cg + 0]));
      float f1 = fmaxf(0.f, fmaf(bf2f((u16)(v.x >> 16)),    cfa[cg + 1], cfc[cg + 1]));
      float f2 = fmaxf(0.f, fmaf(bf2f((u16)(v.y & 0xffff)), cfa[cg + 2], cfc[cg + 2]));
      float f3 = fmaxf(0.f, fmaf(bf2f((u16)(v.y >> 16)),    cfa[cg + 3], cfc[cg + 3]));
      float f4 = fmaxf(0.f, fmaf(bf2f((u16)(v.z & 0xffff)), cfa[cg + 4], cfc[cg + 4]));
      float f5 = fmaxf(0.f, fmaf(bf2f((u16)(v.z >> 16)),    cfa[cg + 5], cfc[cg + 5]));
      float f6 = fmaxf(0.f, fmaf(bf2f((u16)(v.w & 0xffff)), cfa[cg + 6], cfc[cg + 6]));
      float f7 = fmaxf(0.f, fmaf(bf2f((u16)(v.w >> 16)),    cfa[cg + 7], cfc[cg + 7]));
      uint4 o;
      o.x = (unsigned int)f2bf(f0) | ((unsigned int)f2bf(f1) << 16);
      o.y = (unsigned int)f2bf(f2) | ((unsigned int)f2bf(f3) << 16);
      o.z = (unsigned int)f2bf(f4) | ((unsigned int)f2bf(f5) << 16);
      o.w = (unsigned int)f2bf(f6) | ((unsigned int)f2bf(f7) << 16);
      *(uint4*)&Bs[buf][row][cb] = o;
    }
  };

  gload(0);
  __syncthreads();     // cfa/cfc ready
  sstore(0);
  __syncthreads();

  for (int kt = 0; kt < 8; ++kt) {
    const int cur = kt & 1;
    if (kt < 7) gload((kt + 1) << 5);

    bf16x8 af[4], bfv[4];
    #pragma unroll
    for (int f = 0; f < 4; ++f)
      af[f] = __builtin_bit_cast(bf16x8, *(const short8_*)&As[cur][wo * 64 + f * 16 + m][g * 8]);
    #pragma unroll
    for (int f = 0; f < 4; ++f)
      bfv[f] = __builtin_bit_cast(bf16x8, *(const short8_*)&Bs[cur][wn * 64 + f * 16 + m][g * 8]);
    #pragma unroll
    for (int i = 0; i < 4; ++i)
      #pragma unroll
      for (int j = 0; j < 4; ++j)
        acc[i][j] = __builtin_amdgcn_mfma_f32_16x16x32_bf16(af[i], bfv[j], acc[i][j], 0, 0, 0);

    if (kt < 7) sstore(cur ^ 1);
    __syncthreads();
  }

  #pragma unroll
  for (int of = 0; of < 4; ++of) {
    const int pb = wo * 64 + of * 16 + g * 4;
    float bias[4], s1[4], s2[4];
    #pragma unroll
    for (int r = 0; r < 4; ++r) { bias[r] = b1[pb + r]; s1[r] = 0.f; s2[r] = 0.f; }
    #pragma unroll
    for (int nf = 0; nf < 4; ++nf) {
      const int n = n0 + wn * 64 + nf * 16 + m;
      #pragma unroll
      for (int r = 0; r < 4; ++r) {
        float y = acc[of][nf][r] + bias[r];
        s1[r] += y; s2[r] += y * y;
        y1b[((size_t)bz * C2_ + pb + r) * N_ + n] = f2bf(y);
      }
    }
    #pragma unroll
    for (int mk = 1; mk < 16; mk <<= 1)
      #pragma unroll
      for (int r = 0; r < 4; ++r) {
        s1[r] += __shfl_xor(s1[r], mk);
        s2[r] += __shfl_xor(s2[r], mk);
      }
    if (m == 0) {
      #pragma unroll
      for (int r = 0; r < 4; ++r) {
        atomicAdd(&stats[pb + r], s1[r]);
        atomicAdd(&stats[C2_ + pb + r], s2[r]);
      }
    }
  }
}

// ---------------------------------------------------------------------------
__global__ void bn_coef_kernel(const float* __restrict__ g, const float* __restrict__ be,
                               const float* __restrict__ stats, float* __restrict__ coef,
                               int C)
{
  int o = threadIdx.x;
  if (o < C) {
    const float invM = 1.0f / 65536.0f;   // B*N
    float mean = stats[o] * invM;
    float var  = stats[C + o] * invM - mean * mean;
    float a = g[o] / sqrtf(var + BN_EPS);
    float c = be[o] - mean * a;
    coef[o] = a;
    coef[C + o] = c;
  }
}

__global__ void zero_kernel(float* __restrict__ p, int n)
{
  int i = blockIdx.x * blockDim.x + threadIdx.x;
  if (i < n) p[i] = 0.0f;
}

// ---------------------------------------------------------------------------
// final: BN1 + ReLU elementwise, bf16 in -> fp32 out
// ---------------------------------------------------------------------------
__global__ __launch_bounds__(256) void final_kernel(
    const u16* __restrict__ y1b, const float* __restrict__ cf, float* __restrict__ out)
{
  const size_t total4 = (size_t)B_ * C2_ * N_ / 4;
  const size_t stride = (size_t)gridDim.x * blockDim.x;
  for (size_t f = (size_t)blockIdx.x * blockDim.x + threadIdx.x; f < total4; f += stride) {
    size_t base = f * 4;
    int p = (int)((base >> 13) & (C2_ - 1));
    float a = cf[p], c = cf[C2_ + p];
    uint2 v = *(const uint2*)(y1b + base);
    float4 r;
    r.x = fmaxf(0.0f, fmaf(bf2f((u16)(v.x & 0xffff)), a, c));
    r.y = fmaxf(0.0f, fmaf(bf2f((u16)(v.x >> 16)),    a, c));
    r.z = fmaxf(0.0f, fmaf(bf2f((u16)(v.y & 0xffff)), a, c));
    r.w = fmaxf(0.0f, fmaf(bf2f((u16)(v.y >> 16)),    a, c));
    *(float4*)(out + base) = r;
  }
}

// ---------------------------------------------------------------------------
extern "C" void kernel_launch(void* const* d_in, const int* in_sizes, int n_in,
                              void* d_out, int out_size, void* d_ws, size_t ws_size,
                              hipStream_t stream)
{
  const float* xyz_sa     = (const float*)d_in[0];
  const float* xyz_now    = (const float*)d_in[1];
  const float* points_sa  = (const float*)d_in[2];
  const float* points_now = (const float*)d_in[3];
  const float* W0  = (const float*)d_in[4];
  const float* b0  = (const float*)d_in[5];
  const float* g0  = (const float*)d_in[6];
  const float* be0 = (const float*)d_in[7];
  const float* W1  = (const float*)d_in[8];
  const float* b1  = (const float*)d_in[9];
  const float* g1  = (const float*)d_in[10];
  const float* be1 = (const float*)d_in[11];

  const size_t MB = 1048576ull;
  char* base = (char*)d_ws;
  u16*   interpT = (u16*)(base + 0);          // [B][N][256] bf16  32MB
  u16*   psaT    = (u16*)(base + 32 * MB);    // [B][N][128] bf16  16MB
  float* pnT     = (float*)(base + 48 * MB);  // [B][S][256] f32   16MB (dead after knn)
  u16*   y1b     = (u16*)(base + 48 * MB);    // [B][C2][N] bf16   16MB (overlays pnT)
  u16*   y0b     = (u16*)(base + 64 * MB);    // [B][N][256] bf16  32MB
  u16*   W0b     = (u16*)(base + 96 * MB);    // 98304 bf16
  u16*   W1b     = (u16*)(base + 96 * MB + 512 * 1024); // 32768 bf16
  float* stats   = (float*)(base + 97 * MB);  // 768 f
  float* coef    = stats + 768;               // 768 f
  float* out     = (float*)d_out;

  hipLaunchKernelGGL(zero_kernel, dim3(1), dim3(768), 0, stream, stats, 768);
  hipLaunchKernelGGL(cvt_bf16_kernel, dim3((C1_ * C0_ + 255) / 256), dim3(256), 0, stream,
                     W0, W0b, C1_ * C0_);
  hipLaunchKernelGGL(cvt_bf16_kernel, dim3((C2_ * C1_ + 255) / 256), dim3(256), 0, stream,
                     W1, W1b, C2_ * C1_);
  hipLaunchKernelGGL(transpose_kernel, dim3(S_ / 32, D2_ / 32, B_), dim3(256), 0, stream,
                     points_now, pnT);
  hipLaunchKernelGGL(psaT_kernel, dim3(N_ / 32, D1_ / 32, B_), dim3(256), 0, stream,
                     points_sa, psaT);
  hipLaunchKernelGGL(knn_interp_kernel, dim3(N_ / 128, B_), dim3(256), 0, stream,
                     xyz_sa, xyz_now, pnT, interpT);
  hipLaunchKernelGGL(gemm1_mfma_kernel, dim3(N_ / 128, 2, B_), dim3(256), 0, stream,
                     psaT, interpT, W0b, b0, y0b, stats);
  hipLaunchKernelGGL(bn_coef_kernel, dim3(1), dim3(256), 0, stream,
                     g0, be0, stats, coef, C1_);
  hipLaunchKernelGGL(gemm2_mfma_kernel, dim3(N_ / 128, 1, B_), dim3(256), 0, stream,
                     y0b, coef, W1b, b1, y1b, stats + 512);
  hipLaunchKernelGGL(bn_coef_kernel, dim3(1), dim3(128), 0, stream,
                     g1, be1, stats + 512, coef + 512, C2_);
  hipLaunchKernelGGL(final_kernel, dim3(2048), dim3(256), 0, stream,
                     y1b, coef + 512, out);
}